// Round 1
// baseline (1343.529 us; speedup 1.0000x reference)
//
#include <hip/hip_runtime.h>

// RealNVP forward, fused across all 8 coupling layers.
// B=131072 rows, D=64, H=256, L=8. out = y[B*D] ++ logdet[B], fp32.
//
// Design:
//  - cvt_kernel: fp32 weights -> fp16 into d_ws (3 MB). Weights fit in per-XCD L2.
//  - flow_kernel: 1024 blocks x 512 threads; each block carries BM=128 rows
//    through all layers with state (y, activations, s, logdet) in LDS.
//  - Matmuls via v_mfma_f32_16x16x32_f16. Both A (act rows) and B (weight rows,
//    stored [out,in] row-major) load 8 contiguous-k halfs at [lane&15][quad*8+j];
//    C/D: row=(lane>>4)*4+reg, col=lane&15 (measured layouts, m89/m91).
//  - 8 waves = 2(m-halves) x 4(n-quarters) tiling: balances LDS A-frag traffic
//    (~13.8K cyc/CU/layer) vs MFMA (~14.9K cyc/CU/layer).
//  - fp16 chosen over bf16: same MFMA rate, 8x tighter mantissa -> absmax ~1e-2
//    vs the 1.675e-1 threshold. Residuals (xm = y*mask) recomputed in fp32.
//  - tanh = (e-1)/(e+1) via __expf + v_rcp (fast path; libm tanhf would cost
//    more VALU cycles than all MFMAs combined at 1.14e9 calls).

#define BATCH    131072
#define DIM      64
#define HID      256
#define NLAYER   8
#define BM       128
#define NTHREADS 512

typedef _Float16 f16;
typedef __attribute__((ext_vector_type(8))) _Float16 f16x8;
typedef __attribute__((ext_vector_type(4))) _Float16 f16x4;
typedef __attribute__((ext_vector_type(4))) float    f32x4;

__device__ __forceinline__ float tanh_fast(float x) {
  float xc = fminf(fmaxf(x, -15.f), 15.f);      // exp(30) finite; tanh(15)==1 in f32
  float e  = __expf(2.f * xc);                  // v_mul + v_exp_f32
  return (e - 1.f) * __builtin_amdgcn_rcpf(e + 1.f);
}

__global__ void cvt_kernel(const float* __restrict__ s, f16* __restrict__ d, int n4) {
  int i = blockIdx.x * blockDim.x + threadIdx.x;
  if (i >= n4) return;
  float4 v = ((const float4*)s)[i];
  f16x4 o;
  o[0] = (f16)v.x; o[1] = (f16)v.y; o[2] = (f16)v.z; o[3] = (f16)v.w;
  ((f16x4*)d)[i] = o;
}

__global__ __launch_bounds__(NTHREADS, 2) void flow_kernel(
    const float* __restrict__ x, const float* __restrict__ masks,
    const f16* __restrict__ wS1, const f16* __restrict__ wS2, const f16* __restrict__ wS3,
    const float* __restrict__ sb1, const float* __restrict__ sb2, const float* __restrict__ sb3,
    const float* __restrict__ scl,
    const f16* __restrict__ wT1, const f16* __restrict__ wT2, const f16* __restrict__ wT3,
    const float* __restrict__ tb1, const float* __restrict__ tb2, const float* __restrict__ tb3,
    float* __restrict__ y_out, float* __restrict__ ld_out)
{
  // Row pads: +8 halfs / +1 float turn the 16-lane b128 column stride into a
  // 2-way bank alias (free, m136) instead of a full 16-way conflict.
  __shared__ __attribute__((aligned(16))) float y_s [BM][DIM + 1];   // flow state (fp32)
  __shared__ __attribute__((aligned(16))) float s3_s[BM][DIM + 1];   // scaled s output
  __shared__ __attribute__((aligned(16))) f16   xm_s[BM][DIM + 8];   // masked input (fp16 A-operand)
  __shared__ __attribute__((aligned(16))) f16   act [BM][HID + 8];   // hidden activations
  __shared__ float ld_s[BM];

  const int tid  = threadIdx.x;
  const int lane = tid & 63;
  const int wv   = tid >> 6;      // wave 0..7
  const int mi   = wv >> 2;       // m-half: rows [mi*64, mi*64+64)
  const int ni   = wv & 3;        // n-quarter
  const int quad = lane >> 4;
  const int l16  = lane & 15;
  const int row0 = blockIdx.x * BM;

  for (int i = tid; i < BM * DIM; i += NTHREADS)
    y_s[i >> 6][i & 63] = x[(size_t)row0 * DIM + i];
  if (tid < BM) ld_s[tid] = 0.f;
  __syncthreads();

  const f32x4 fzero = {0.f, 0.f, 0.f, 0.f};

  #pragma unroll 1
  for (int l = 0; l < NLAYER; ++l) {
    const float* mrow = masks + l * DIM;
    const f16* W1p[2] = { wS1 + l * HID * DIM, wT1 + l * HID * DIM };
    const f16* W2p[2] = { wS2 + l * HID * HID, wT2 + l * HID * HID };
    const f16* W3p[2] = { wS3 + l * DIM * HID, wT3 + l * DIM * HID };
    const float* b1p[2] = { sb1 + l * HID, tb1 + l * HID };
    const float* b2p[2] = { sb2 + l * HID, tb2 + l * HID };
    const float* b3p[2] = { sb3 + l * DIM, tb3 + l * DIM };
    const float* sclr = scl + l * DIM;

    // xm = y * mask (fp32 -> fp16 once; epilogues recompute xm in fp32)
    for (int i = tid; i < BM * DIM; i += NTHREADS) {
      int r = i >> 6, d = i & 63;
      xm_s[r][d] = (f16)(y_s[r][d] * mrow[d]);
    }
    __syncthreads();

    #pragma unroll 1
    for (int net = 0; net < 2; ++net) {   // net 0 = scale MLP, net 1 = translation MLP
      const f16* W1 = W1p[net]; const f16* W2 = W2p[net]; const f16* W3 = W3p[net];
      const float* b1 = b1p[net]; const float* b2 = b2p[net]; const float* b3 = b3p[net];

      f32x4 acc[4][4];
      #pragma unroll
      for (int m = 0; m < 4; ++m)
        #pragma unroll
        for (int n = 0; n < 4; ++n) acc[m][n] = fzero;

      // ---- mm1: xm[128,64] @ W1^T -> act[128,256] ----
      #pragma unroll
      for (int kt = 0; kt < 2; ++kt) {
        const int k0 = kt * 32 + quad * 8;
        f16x8 afr[4], bfr[4];
        #pragma unroll
        for (int m = 0; m < 4; ++m)
          afr[m] = *(const f16x8*)&xm_s[(mi * 4 + m) * 16 + l16][k0];
        #pragma unroll
        for (int n = 0; n < 4; ++n)
          bfr[n] = *(const f16x8*)&W1[(ni * 64 + n * 16 + l16) * DIM + k0];
        #pragma unroll
        for (int m = 0; m < 4; ++m)
          #pragma unroll
          for (int n = 0; n < 4; ++n)
            acc[m][n] = __builtin_amdgcn_mfma_f32_16x16x32_f16(afr[m], bfr[n], acc[m][n], 0, 0, 0);
      }
      // epilogue: act = tanh(. + b1). Safe without pre-barrier: last act readers
      // were separated by the mm3-kloop / end-of-layer barriers below.
      #pragma unroll
      for (int m = 0; m < 4; ++m) {
        const int mr = (mi * 4 + m) * 16 + quad * 4;
        #pragma unroll
        for (int n = 0; n < 4; ++n) {
          const int nc = ni * 64 + n * 16 + l16;
          const float bias = b1[nc];
          #pragma unroll
          for (int r = 0; r < 4; ++r)
            act[mr + r][nc] = (f16)tanh_fast(acc[m][n][r] + bias);
        }
      }
      __syncthreads();

      // ---- mm2: act[128,256] @ W2^T -> act (residual tanh) ----
      #pragma unroll
      for (int m = 0; m < 4; ++m)
        #pragma unroll
        for (int n = 0; n < 4; ++n) acc[m][n] = fzero;
      #pragma unroll
      for (int kt = 0; kt < 8; ++kt) {
        const int k0 = kt * 32 + quad * 8;
        f16x8 afr[4], bfr[4];
        #pragma unroll
        for (int m = 0; m < 4; ++m)
          afr[m] = *(const f16x8*)&act[(mi * 4 + m) * 16 + l16][k0];
        #pragma unroll
        for (int n = 0; n < 4; ++n)
          bfr[n] = *(const f16x8*)&W2[(ni * 64 + n * 16 + l16) * HID + k0];
        #pragma unroll
        for (int m = 0; m < 4; ++m)
          #pragma unroll
          for (int n = 0; n < 4; ++n)
            acc[m][n] = __builtin_amdgcn_mfma_f32_16x16x32_f16(afr[m], bfr[n], acc[m][n], 0, 0, 0);
      }
      __syncthreads();   // all waves done READING act before it is overwritten
      #pragma unroll
      for (int m = 0; m < 4; ++m) {
        const int mr = (mi * 4 + m) * 16 + quad * 4;
        #pragma unroll
        for (int n = 0; n < 4; ++n) {
          const int nc = ni * 64 + n * 16 + l16;
          const float bias = b2[nc];
          #pragma unroll
          for (int r = 0; r < 4; ++r) {
            const float prev = (float)act[mr + r][nc];   // own region: read-before-write
            act[mr + r][nc] = (f16)tanh_fast(acc[m][n][r] + bias + prev);
          }
        }
      }
      __syncthreads();

      // ---- mm3: act[128,256] @ W3^T -> [128,64] ----
      f32x4 acc3[4];
      #pragma unroll
      for (int m = 0; m < 4; ++m) acc3[m] = fzero;
      #pragma unroll
      for (int kt = 0; kt < 8; ++kt) {
        const int k0 = kt * 32 + quad * 8;
        const f16x8 bfr = *(const f16x8*)&W3[(ni * 16 + l16) * HID + k0];
        #pragma unroll
        for (int m = 0; m < 4; ++m) {
          const f16x8 afr = *(const f16x8*)&act[(mi * 4 + m) * 16 + l16][k0];
          acc3[m] = __builtin_amdgcn_mfma_f32_16x16x32_f16(afr, bfr, acc3[m], 0, 0, 0);
        }
      }
      __syncthreads();   // act now free for the other net / next layer

      const int   d    = ni * 16 + l16;   // this wave's output column (fixed per lane)
      const float mval = mrow[d];
      const float b3v  = b3[d];
      if (net == 0) {
        const float sv = sclr[d];
        #pragma unroll
        for (int m = 0; m < 4; ++m) {
          const int mr = (mi * 4 + m) * 16 + quad * 4;
          #pragma unroll
          for (int r = 0; r < 4; ++r) {
            const float xmv = y_s[mr + r][d] * mval;            // fp32 residual
            s3_s[mr + r][d] = (tanh_fast(acc3[m][r] + b3v) + xmv) * sv;
          }
        }
      } else {
        // translation epilogue + coupling update, all in-register/LDS
        #pragma unroll
        for (int m = 0; m < 4; ++m) {
          const int mr = (mi * 4 + m) * 16 + quad * 4;
          #pragma unroll
          for (int r = 0; r < 4; ++r) {
            const float yv = y_s[mr + r][d];
            const float tv = acc3[m][r] + b3v + yv * mval;      // t + xm
            const float e  = __expf(s3_s[mr + r][d]);
            y_s[mr + r][d] = mval * yv + (1.f - mval) * (yv * e + tv);
          }
        }
      }
    } // net
    __syncthreads();

    // logdet += sum_d (1-m[d]) * s[d]; s3_s stable until next layer's mm3-s epilogue
    if (tid < BM) {
      float a = 0.f;
      #pragma unroll
      for (int dd = 0; dd < DIM; ++dd)
        a += (1.f - mrow[dd]) * s3_s[tid][dd];
      ld_s[tid] += a;
    }
  } // layers
  __syncthreads();

  for (int i = tid; i < BM * DIM; i += NTHREADS)
    y_out[(size_t)row0 * DIM + i] = y_s[i >> 6][i & 63];
  if (tid < BM) ld_out[row0 + tid] = ld_s[tid];
}

extern "C" void kernel_launch(void* const* d_in, const int* in_sizes, int n_in,
                              void* d_out, int out_size, void* d_ws, size_t ws_size,
                              hipStream_t stream) {
  const float* x     = (const float*)d_in[0];
  const float* masks = (const float*)d_in[1];
  const float* sW1f  = (const float*)d_in[2];
  const float* sb1   = (const float*)d_in[3];
  const float* sW2f  = (const float*)d_in[4];
  const float* sb2   = (const float*)d_in[5];
  const float* sW3f  = (const float*)d_in[6];
  const float* sb3   = (const float*)d_in[7];
  const float* scl   = (const float*)d_in[8];
  const float* tW1f  = (const float*)d_in[9];
  const float* tb1   = (const float*)d_in[10];
  const float* tW2f  = (const float*)d_in[11];
  const float* tb2   = (const float*)d_in[12];
  const float* tW3f  = (const float*)d_in[13];
  const float* tb3   = (const float*)d_in[14];
  (void)in_sizes; (void)n_in; (void)out_size; (void)ws_size;

  // fp16 weight pack in workspace (re-converted every call; ws is re-poisoned).
  const int W1SZ = NLAYER * HID * DIM;   // 131072
  const int W2SZ = NLAYER * HID * HID;   // 524288
  const int W3SZ = NLAYER * DIM * HID;   // 131072  -> total 3,145,728 bytes
  f16* wb  = (f16*)d_ws;
  f16* wS1 = wb;
  f16* wS2 = wS1 + W1SZ;
  f16* wS3 = wS2 + W2SZ;
  f16* wT1 = wS3 + W3SZ;
  f16* wT2 = wT1 + W1SZ;
  f16* wT3 = wT2 + W2SZ;

  cvt_kernel<<<W1SZ / 4 / 256, 256, 0, stream>>>(sW1f, wS1, W1SZ / 4);
  cvt_kernel<<<W2SZ / 4 / 256, 256, 0, stream>>>(sW2f, wS2, W2SZ / 4);
  cvt_kernel<<<W3SZ / 4 / 256, 256, 0, stream>>>(sW3f, wS3, W3SZ / 4);
  cvt_kernel<<<W1SZ / 4 / 256, 256, 0, stream>>>(tW1f, wT1, W1SZ / 4);
  cvt_kernel<<<W2SZ / 4 / 256, 256, 0, stream>>>(tW2f, wT2, W2SZ / 4);
  cvt_kernel<<<W3SZ / 4 / 256, 256, 0, stream>>>(tW3f, wT3, W3SZ / 4);

  float* y_out  = (float*)d_out;
  float* ld_out = y_out + (size_t)BATCH * DIM;
  flow_kernel<<<BATCH / BM, NTHREADS, 0, stream>>>(
      x, masks, wS1, wS2, wS3, sb1, sb2, sb3, scl,
      wT1, wT2, wT3, tb1, tb2, tb3, y_out, ld_out);
}

// Round 2
// 1060.594 us; speedup vs baseline: 1.2668x; 1.2668x over previous
//
#include <hip/hip_runtime.h>

// RealNVP forward, fused across all 8 coupling layers.  Round 2.
// B=131072, D=64, H=256, L=8. out = y[B*D] ++ logdet[B], fp32.
//
// R1 -> R2 changes (theory: kill the ~50% barrier-stall seen at 1-block/CU):
//  - BM 128->64, block 512->256 threads (4 waves, one per n-quarter).
//  - y, s3, logdet-acc moved LDS->registers: they live in the MFMA C-fragment
//    lane mapping (row = m*16+quad*4+reg, col = wv*16+l16) and are produced and
//    consumed by the SAME lane -> zero cross-lane traffic.
//  - LDS 153 KB -> ~44 KB -> 3 blocks/CU co-resident (__launch_bounds__(256,3)):
//    barrier drains of one block overlap compute of the other two.
//  - tanh = 1 - 2*rcp(exp2(c*x)+1): correct +-1 limits at inf -> no clamps,
//    5 instrs (mul, exp2, add, rcp, fma), 2 transcendental.
//  - logdet: per-lane register accumulate; one 16-lane shfl butterfly at end.

#define BATCH    131072
#define DIM      64
#define HID      256
#define NLAYER   8
#define BM       64
#define NTHREADS 256

typedef _Float16 f16;
typedef __attribute__((ext_vector_type(8))) _Float16 f16x8;
typedef __attribute__((ext_vector_type(4))) _Float16 f16x4;
typedef __attribute__((ext_vector_type(4))) float    f32x4;

#define TWO_LOG2E 2.8853900817779268f   // 2*log2(e)
#define LOG2E     1.4426950408889634f

__device__ __forceinline__ float tanh_fast(float x) {
  // tanh(x) = 1 - 2/(e^{2x}+1);  e^{2x} = 2^{x*2log2e}
  // x->+inf: exp2=inf, rcp=0 -> 1.  x->-inf: exp2=0, rcp(1)=1 -> -1.  No clamps.
  float e = __builtin_amdgcn_exp2f(x * TWO_LOG2E);
  return 1.f - 2.f * __builtin_amdgcn_rcpf(e + 1.f);
}

__global__ void cvt_kernel(const float* __restrict__ s, f16* __restrict__ d, int n4) {
  int i = blockIdx.x * blockDim.x + threadIdx.x;
  if (i >= n4) return;
  float4 v = ((const float4*)s)[i];
  f16x4 o;
  o[0] = (f16)v.x; o[1] = (f16)v.y; o[2] = (f16)v.z; o[3] = (f16)v.w;
  ((f16x4*)d)[i] = o;
}

__global__ __launch_bounds__(NTHREADS, 3) void flow_kernel(
    const float* __restrict__ x, const float* __restrict__ masks,
    const f16* __restrict__ wS1, const f16* __restrict__ wS2, const f16* __restrict__ wS3,
    const float* __restrict__ sb1, const float* __restrict__ sb2, const float* __restrict__ sb3,
    const float* __restrict__ scl,
    const f16* __restrict__ wT1, const f16* __restrict__ wT2, const f16* __restrict__ wT3,
    const float* __restrict__ tb1, const float* __restrict__ tb2, const float* __restrict__ tb3,
    float* __restrict__ y_out, float* __restrict__ ld_out)
{
  // Row pads keep b128 A-frag reads 16B-aligned; 44 KB total -> 3 blocks/CU.
  __shared__ __attribute__((aligned(16))) f16   xm_s[BM][DIM + 8];   //  9.2 KB
  __shared__ __attribute__((aligned(16))) f16   act [BM][HID + 8];   // 33.8 KB
  __shared__ float ld_red[BM][4];                                    //  1.0 KB

  const int tid  = threadIdx.x;
  const int lane = tid & 63;
  const int wv   = tid >> 6;        // wave 0..3 = n-quarter
  const int quad = lane >> 4;
  const int l16  = lane & 15;
  const int row0 = blockIdx.x * BM;
  const int d    = wv * 16 + l16;   // this wave's D-column (mm3/C-tile)

  // Per-lane state in MFMA C-layout: cell (m,r) = row m*16+quad*4+r, col d.
  float yv[4][4], s3r[4][4], lda[4][4];
  #pragma unroll
  for (int m = 0; m < 4; ++m)
    #pragma unroll
    for (int r = 0; r < 4; ++r) {
      yv[m][r]  = x[(size_t)(row0 + m * 16 + quad * 4 + r) * DIM + d];
      lda[m][r] = 0.f;
    }

  const f32x4 fzero = {0.f, 0.f, 0.f, 0.f};

  #pragma unroll 1
  for (int l = 0; l < NLAYER; ++l) {
    const float mval = masks[l * DIM + d];
    const float om   = 1.f - mval;

    // xm = y*mask into LDS (A-operand for mm1), fp16
    #pragma unroll
    for (int m = 0; m < 4; ++m)
      #pragma unroll
      for (int r = 0; r < 4; ++r)
        xm_s[m * 16 + quad * 4 + r][d] = (f16)(yv[m][r] * mval);
    __syncthreads();                                     // (1) xm ready

    #pragma unroll 1
    for (int net = 0; net < 2; ++net) {
      const f16*   W1 = (net ? wT1 : wS1) + l * HID * DIM;
      const f16*   W2 = (net ? wT2 : wS2) + l * HID * HID;
      const f16*   W3 = (net ? wT3 : wS3) + l * DIM * HID;
      const float* b1 = (net ? tb1 : sb1) + l * HID;
      const float* b2 = (net ? tb2 : sb2) + l * HID;
      const float* b3 = (net ? tb3 : sb3) + l * DIM;

      f32x4 acc[4][4];
      #pragma unroll
      for (int m = 0; m < 4; ++m)
        #pragma unroll
        for (int n = 0; n < 4; ++n) acc[m][n] = fzero;

      // ---- mm1: xm[64,64] @ W1^T -> act[64,256] ----
      #pragma unroll
      for (int kt = 0; kt < 2; ++kt) {
        const int k0 = kt * 32 + quad * 8;
        f16x8 afr[4], bfr[4];
        #pragma unroll
        for (int m = 0; m < 4; ++m)
          afr[m] = *(const f16x8*)&xm_s[m * 16 + l16][k0];
        #pragma unroll
        for (int n = 0; n < 4; ++n)
          bfr[n] = *(const f16x8*)&W1[(wv * 64 + n * 16 + l16) * DIM + k0];
        #pragma unroll
        for (int m = 0; m < 4; ++m)
          #pragma unroll
          for (int n = 0; n < 4; ++n)
            acc[m][n] = __builtin_amdgcn_mfma_f32_16x16x32_f16(afr[m], bfr[n], acc[m][n], 0, 0, 0);
      }
      // act readers of the previous net/layer finished at their post-mm3 barrier.
      #pragma unroll
      for (int n = 0; n < 4; ++n) {
        const int   nc   = wv * 64 + n * 16 + l16;
        const float bias = b1[nc];
        #pragma unroll
        for (int m = 0; m < 4; ++m) {
          const int mr = m * 16 + quad * 4;
          #pragma unroll
          for (int r = 0; r < 4; ++r)
            act[mr + r][nc] = (f16)tanh_fast(acc[m][n][r] + bias);
        }
      }
      __syncthreads();                                   // (2) h1 ready

      // ---- mm2: act[64,256] @ W2^T (+residual) -> act ----
      #pragma unroll
      for (int m = 0; m < 4; ++m)
        #pragma unroll
        for (int n = 0; n < 4; ++n) acc[m][n] = fzero;
      #pragma unroll
      for (int kt = 0; kt < 8; ++kt) {
        const int k0 = kt * 32 + quad * 8;
        f16x8 afr[4], bfr[4];
        #pragma unroll
        for (int m = 0; m < 4; ++m)
          afr[m] = *(const f16x8*)&act[m * 16 + l16][k0];
        #pragma unroll
        for (int n = 0; n < 4; ++n)
          bfr[n] = *(const f16x8*)&W2[(wv * 64 + n * 16 + l16) * HID + k0];
        #pragma unroll
        for (int m = 0; m < 4; ++m)
          #pragma unroll
          for (int n = 0; n < 4; ++n)
            acc[m][n] = __builtin_amdgcn_mfma_f32_16x16x32_f16(afr[m], bfr[n], acc[m][n], 0, 0, 0);
      }
      __syncthreads();                                   // (3) all done reading act
      #pragma unroll
      for (int n = 0; n < 4; ++n) {
        const int   nc   = wv * 64 + n * 16 + l16;
        const float bias = b2[nc];
        #pragma unroll
        for (int m = 0; m < 4; ++m) {
          const int mr = m * 16 + quad * 4;
          #pragma unroll
          for (int r = 0; r < 4; ++r) {
            const float prev = (float)act[mr + r][nc];   // own C-cell: same wave wrote it
            act[mr + r][nc] = (f16)tanh_fast(acc[m][n][r] + bias + prev);
          }
        }
      }
      __syncthreads();                                   // (4) h2 ready

      // ---- mm3: act[64,256] @ W3^T -> [64,64] ----
      f32x4 acc3[4];
      #pragma unroll
      for (int m = 0; m < 4; ++m) acc3[m] = fzero;
      #pragma unroll
      for (int kt = 0; kt < 8; ++kt) {
        const int k0 = kt * 32 + quad * 8;
        const f16x8 bfr = *(const f16x8*)&W3[d * HID + k0];
        #pragma unroll
        for (int m = 0; m < 4; ++m) {
          const f16x8 afr = *(const f16x8*)&act[m * 16 + l16][k0];
          acc3[m] = __builtin_amdgcn_mfma_f32_16x16x32_f16(afr, bfr, acc3[m], 0, 0, 0);
        }
      }
      __syncthreads();                                   // (5) act free for next writer

      const float b3v = b3[d];
      if (net == 0) {
        const float sv = scl[l * DIM + d];
        #pragma unroll
        for (int m = 0; m < 4; ++m)
          #pragma unroll
          for (int r = 0; r < 4; ++r)
            s3r[m][r] = (tanh_fast(acc3[m][r] + b3v) + yv[m][r] * mval) * sv;
      } else {
        #pragma unroll
        for (int m = 0; m < 4; ++m)
          #pragma unroll
          for (int r = 0; r < 4; ++r) {
            const float y0 = yv[m][r];
            const float tv = acc3[m][r] + b3v + y0 * mval;          // t + xm (no tanh)
            const float e  = __builtin_amdgcn_exp2f(s3r[m][r] * LOG2E);
            yv[m][r]  = mval * y0 + om * (y0 * e + tv);
            lda[m][r] += om * s3r[m][r];
          }
      }
    } // net
  } // layers

  // y out (registers -> global, C-layout scatter; 34 MB total, ~free)
  #pragma unroll
  for (int m = 0; m < 4; ++m)
    #pragma unroll
    for (int r = 0; r < 4; ++r)
      y_out[(size_t)(row0 + m * 16 + quad * 4 + r) * DIM + d] = yv[m][r];

  // logdet: butterfly over the 16 l16-lanes (stays within quad group), then
  // combine the 4 waves via LDS.
  #pragma unroll
  for (int m = 0; m < 4; ++m)
    #pragma unroll
    for (int r = 0; r < 4; ++r) {
      float v = lda[m][r];
      v += __shfl_xor(v, 1);
      v += __shfl_xor(v, 2);
      v += __shfl_xor(v, 4);
      v += __shfl_xor(v, 8);
      if (l16 == 0) ld_red[m * 16 + quad * 4 + r][wv] = v;
    }
  __syncthreads();
  if (tid < BM)
    ld_out[row0 + tid] = ld_red[tid][0] + ld_red[tid][1] + ld_red[tid][2] + ld_red[tid][3];
}

extern "C" void kernel_launch(void* const* d_in, const int* in_sizes, int n_in,
                              void* d_out, int out_size, void* d_ws, size_t ws_size,
                              hipStream_t stream) {
  const float* x     = (const float*)d_in[0];
  const float* masks = (const float*)d_in[1];
  const float* sW1f  = (const float*)d_in[2];
  const float* sb1   = (const float*)d_in[3];
  const float* sW2f  = (const float*)d_in[4];
  const float* sb2   = (const float*)d_in[5];
  const float* sW3f  = (const float*)d_in[6];
  const float* sb3   = (const float*)d_in[7];
  const float* scl   = (const float*)d_in[8];
  const float* tW1f  = (const float*)d_in[9];
  const float* tb1   = (const float*)d_in[10];
  const float* tW2f  = (const float*)d_in[11];
  const float* tb2   = (const float*)d_in[12];
  const float* tW3f  = (const float*)d_in[13];
  const float* tb3   = (const float*)d_in[14];
  (void)in_sizes; (void)n_in; (void)out_size; (void)ws_size;

  const int W1SZ = NLAYER * HID * DIM;   // 131072
  const int W2SZ = NLAYER * HID * HID;   // 524288
  const int W3SZ = NLAYER * DIM * HID;   // 131072
  f16* wS1 = (f16*)d_ws;
  f16* wS2 = wS1 + W1SZ;
  f16* wS3 = wS2 + W2SZ;
  f16* wT1 = wS3 + W3SZ;
  f16* wT2 = wT1 + W1SZ;
  f16* wT3 = wT2 + W2SZ;

  cvt_kernel<<<W1SZ / 4 / 256, 256, 0, stream>>>(sW1f, wS1, W1SZ / 4);
  cvt_kernel<<<W2SZ / 4 / 256, 256, 0, stream>>>(sW2f, wS2, W2SZ / 4);
  cvt_kernel<<<W3SZ / 4 / 256, 256, 0, stream>>>(sW3f, wS3, W3SZ / 4);
  cvt_kernel<<<W1SZ / 4 / 256, 256, 0, stream>>>(tW1f, wT1, W1SZ / 4);
  cvt_kernel<<<W2SZ / 4 / 256, 256, 0, stream>>>(tW2f, wT2, W2SZ / 4);
  cvt_kernel<<<W3SZ / 4 / 256, 256, 0, stream>>>(tW3f, wT3, W3SZ / 4);

  float* y_out  = (float*)d_out;
  float* ld_out = y_out + (size_t)BATCH * DIM;
  flow_kernel<<<BATCH / BM, NTHREADS, 0, stream>>>(
      x, masks, wS1, wS2, wS3, sb1, sb2, sb3, scl,
      wT1, wT2, wT3, tb1, tb2, tb3, y_out, ld_out);
}